// Round 1
// baseline (136.869 us; speedup 1.0000x reference)
//
#include <hip/hip_runtime.h>
#include <math.h>

#define B 512
#define N 256
#define E 1024
#define D 256
#define H 256
#define C 8
#define U 64

// ---------------------------------------------------------------------------
// Mask dtype sniffing: jax bernoulli masks are bool; harness ABI may hand them
// to us as int32 (documented "integer -> int*"), raw bytes, or float32.
// flag: 0 = int32 words, 1 = byte-packed bool, 2 = float32.
// ---------------------------------------------------------------------------
__device__ __forceinline__ float mask_val(const void* m, long i, int flag) {
    if (flag == 1) return ((const unsigned char*)m)[i] ? 1.f : 0.f;
    if (flag == 2) return (((const float*)m)[i] != 0.f) ? 1.f : 0.f;
    return ((const int*)m)[i] ? 1.f : 0.f;
}

__global__ void k_detect(const unsigned int* __restrict__ am, int* __restrict__ flag) {
    __shared__ int cls0, cls1;
    if (threadIdx.x == 0) { cls0 = 0; cls1 = 0; }
    __syncthreads();
    unsigned int w = am[threadIdx.x];  // first 256 words: safe for all layouts
    if (w != 0u && w != 1u) {
        if (w == 0x3f800000u) atomicOr(&cls1, 1);
        else                  atomicOr(&cls0, 1);
    }
    __syncthreads();
    if (threadIdx.x == 0) *flag = cls0 ? 1 : (cls1 ? 2 : 0);
}

// block-wide sum reduction (256 threads)
__device__ __forceinline__ float block_sum(float v, float* red) {
    int t = threadIdx.x;
    red[t] = v; __syncthreads();
    for (int s = 128; s > 0; s >>= 1) {
        if (t < s) red[t] += red[t + s];
        __syncthreads();
    }
    float r = red[0]; __syncthreads();
    return r;
}

// ---------------------------------------------------------------------------
// k_h: per-batch trunk. h = relu(relu(f@Wc1+bc1)@Wc2+bc2); gates; and the
// per-batch layer-1 bases base_n = h@Wn1[:256]+bn1, base_e = h@We1[:256]+be1.
// 4 batch rows per block (weight reuse), 256 threads = one output column each.
// ---------------------------------------------------------------------------
__global__ __launch_bounds__(256) void k_h(
    const float* __restrict__ feat,
    const float* __restrict__ Wc1, const float* __restrict__ bc1,
    const float* __restrict__ Wc2, const float* __restrict__ bc2,
    const float* __restrict__ Wn1, const float* __restrict__ bn1,
    const float* __restrict__ We1, const float* __restrict__ be1,
    const float* __restrict__ Wg,  const float* __restrict__ bg,
    const float* __restrict__ margin, const float* __restrict__ brisk,
    float* __restrict__ base_n, float* __restrict__ base_e,
    float* __restrict__ out_gate)
{
    __shared__ float sa[4][256];
    __shared__ float sb[4][256];
    __shared__ float red[256];
    int t = threadIdx.x;
    int b0 = blockIdx.x * 4;

    #pragma unroll
    for (int r = 0; r < 4; r++) sa[r][t] = feat[(long)(b0 + r) * D + t];
    __syncthreads();

    // layer 1
    float a0, a1, a2, a3;
    a0 = a1 = a2 = a3 = bc1[t];
    for (int d = 0; d < D; d++) {
        float w = Wc1[d * H + t];
        a0 = fmaf(sa[0][d], w, a0);
        a1 = fmaf(sa[1][d], w, a1);
        a2 = fmaf(sa[2][d], w, a2);
        a3 = fmaf(sa[3][d], w, a3);
    }
    sb[0][t] = fmaxf(a0, 0.f); sb[1][t] = fmaxf(a1, 0.f);
    sb[2][t] = fmaxf(a2, 0.f); sb[3][t] = fmaxf(a3, 0.f);
    __syncthreads();

    // layer 2
    a0 = a1 = a2 = a3 = bc2[t];
    for (int d = 0; d < H; d++) {
        float w = Wc2[d * H + t];
        a0 = fmaf(sb[0][d], w, a0);
        a1 = fmaf(sb[1][d], w, a1);
        a2 = fmaf(sb[2][d], w, a2);
        a3 = fmaf(sb[3][d], w, a3);
    }
    __syncthreads();
    sa[0][t] = fmaxf(a0, 0.f); sa[1][t] = fmaxf(a1, 0.f);
    sa[2][t] = fmaxf(a2, 0.f); sa[3][t] = fmaxf(a3, 0.f);
    __syncthreads();   // sa now holds h for the 4 rows

    // per-batch bases for node & edge MLP layer-1 (h part)
    float n0, n1, n2, n3, e0, e1, e2, e3;
    n0 = n1 = n2 = n3 = bn1[t];
    e0 = e1 = e2 = e3 = be1[t];
    for (int j = 0; j < H; j++) {
        float wn = Wn1[j * H + t];
        float we = We1[j * H + t];
        float h0 = sa[0][j], h1 = sa[1][j], h2 = sa[2][j], h3 = sa[3][j];
        n0 = fmaf(h0, wn, n0); n1 = fmaf(h1, wn, n1);
        n2 = fmaf(h2, wn, n2); n3 = fmaf(h3, wn, n3);
        e0 = fmaf(h0, we, e0); e1 = fmaf(h1, we, e1);
        e2 = fmaf(h2, we, e2); e3 = fmaf(h3, we, e3);
    }
    base_n[(long)(b0 + 0) * H + t] = n0;
    base_n[(long)(b0 + 1) * H + t] = n1;
    base_n[(long)(b0 + 2) * H + t] = n2;
    base_n[(long)(b0 + 3) * H + t] = n3;
    base_e[(long)(b0 + 0) * H + t] = e0;
    base_e[(long)(b0 + 1) * H + t] = e1;
    base_e[(long)(b0 + 2) * H + t] = e2;
    base_e[(long)(b0 + 3) * H + t] = e3;

    // gate: sigmoid(h@Wg + bg) per row
    float wg = Wg[t];
    float bgv = bg[0];
    for (int r = 0; r < 4; r++) {
        float s = block_sum(sa[r][t] * wg, red);
        if (t == 0) {
            int b = b0 + r;
            float lg = 1.f / (1.f + expf(-(s + bgv)));
            float rg = ((margin[b] < 0.2f) || (brisk[b] > 0.6f) || (lg > 0.5f)) ? 1.f : 0.f;
            out_gate[b] = rg;
        }
    }
}

// ---------------------------------------------------------------------------
// k_node: 4 batch rows per block (one per wave), each lane handles 4 nodes.
// z_j = base_n[b][j] + sum_k extra[k]*Wn1[256+k][j]; delta = relu(z)@Wn2+bn2.
// Writes raw (uncentered) refined scores to out0.
// ---------------------------------------------------------------------------
__global__ __launch_bounds__(256) void k_node(
    const float* __restrict__ cs, const float* __restrict__ coords,
    const float* __restrict__ unc, const int* __restrict__ actions,
    const void* __restrict__ amask,
    const float* __restrict__ Wn1, const float* __restrict__ Wn2,
    const float* __restrict__ bn2,
    const float* __restrict__ base_n, const float* __restrict__ gate,
    const int* __restrict__ flagp,
    float* __restrict__ out0)
{
    __shared__ float sW[256][12];
    __shared__ float sB[4][256];
    int t = threadIdx.x;
    int b0 = blockIdx.x * 4;
    int flag = *flagp;

    #pragma unroll
    for (int k = 0; k < 10; k++) sW[t][k] = Wn1[(H + k) * H + t];
    sW[t][10] = Wn2[t];
    sW[t][11] = 0.f;
    #pragma unroll
    for (int r = 0; r < 4; r++) sB[r][t] = base_n[(long)(b0 + r) * H + t];
    __syncthreads();

    int w = t >> 6, lane = t & 63;
    int b = b0 + w;
    float g = gate[b];
    float bn2v = bn2[0];

    float f[4][10], acc[4], amv[4];
    #pragma unroll
    for (int q = 0; q < 4; q++) {
        int n = lane + 64 * q;
        const float4* cp = (const float4*)(coords + ((long)b * N + n) * C);
        float4 c0 = cp[0], c1 = cp[1];
        f[q][0] = c0.x; f[q][1] = c0.y; f[q][2] = c0.z; f[q][3] = c0.w;
        f[q][4] = c1.x; f[q][5] = c1.y; f[q][6] = c1.z; f[q][7] = c1.w;
        f[q][8] = cs[(long)b * N + n];
        int a = actions[(long)b * N + n];
        a = min(max(a, 0), U - 1);
        f[q][9] = unc[(long)b * U + a];
        amv[q] = mask_val(amask, (long)b * N + n, flag);
        acc[q] = bn2v;
    }

    for (int j = 0; j < H; j++) {
        float base = sB[w][j];
        float w2 = sW[j][10];
        #pragma unroll
        for (int q = 0; q < 4; q++) {
            float z = base;
            #pragma unroll
            for (int k = 0; k < 10; k++) z = fmaf(f[q][k], sW[j][k], z);
            acc[q] = fmaf(fmaxf(z, 0.f), w2, acc[q]);
        }
    }

    #pragma unroll
    for (int q = 0; q < 4; q++) {
        int n = lane + 64 * q;
        float am = amv[q];
        float nd = acc[q] * am;                       // node_delta * amf
        float raw = (f[q][8] + g * 0.1f * nd) * am;   // (cs + gate*SCALE*nd)*amf
        out0[(long)b * N + n] = raw;
    }
}

// ---------------------------------------------------------------------------
// k_edge: one batch row per block, each thread handles 4 edges.
// Writes refined_edge directly to out2.
// ---------------------------------------------------------------------------
__global__ __launch_bounds__(256) void k_edge(
    const float* __restrict__ es, const float* __restrict__ coords,
    const int* __restrict__ edges, const void* __restrict__ emask,
    const float* __restrict__ We1, const float* __restrict__ We2,
    const float* __restrict__ be2,
    const float* __restrict__ base_e, const float* __restrict__ gate,
    const int* __restrict__ flagp,
    float* __restrict__ out2)
{
    __shared__ float sW[256][12];
    __shared__ float sB[256];
    __shared__ float sC[256][8];
    int t = threadIdx.x;
    int b = blockIdx.x;
    int flag = *flagp;

    #pragma unroll
    for (int k = 0; k < 10; k++) sW[t][k] = We1[(H + k) * H + t];
    sW[t][10] = We2[t];
    sW[t][11] = 0.f;
    sB[t] = base_e[(long)b * H + t];
    {
        float4* sc4 = (float4*)&sC[0][0];
        const float4* g4 = (const float4*)(coords + (long)b * N * C);
        sc4[t] = g4[t];
        sc4[t + 256] = g4[t + 256];
    }
    __syncthreads();

    float g = gate[b];
    float be2v = be2[0];

    float f[4][10], acc[4], emv[4];
    #pragma unroll
    for (int q = 0; q < 4; q++) {
        int e = t + 256 * q;
        int2 ev = ((const int2*)edges)[(long)b * E + e];
        int s0 = min(max(ev.x, 0), N - 1);
        int d0 = min(max(ev.y, 0), N - 1);
        #pragma unroll
        for (int k = 0; k < 8; k++) f[q][k] = sC[d0][k] - sC[s0][k];
        f[q][8] = es[(long)b * E + e];
        emv[q] = mask_val(emask, (long)b * E + e, flag);
        f[q][9] = emv[q];
        acc[q] = be2v;
    }

    for (int j = 0; j < H; j++) {
        float base = sB[j];
        float w2 = sW[j][10];
        #pragma unroll
        for (int q = 0; q < 4; q++) {
            float z = base;
            #pragma unroll
            for (int k = 0; k < 10; k++) z = fmaf(f[q][k], sW[j][k], z);
            acc[q] = fmaf(fmaxf(z, 0.f), w2, acc[q]);
        }
    }

    #pragma unroll
    for (int q = 0; q < 4; q++) {
        int e = t + 256 * q;
        // refined = (es + g*SCALE*(acc*em))*em  ->  em ? es + 0.1g*acc : 0
        float re = (emv[q] != 0.f) ? (f[q][8] + g * 0.1f * acc[q]) : 0.f;
        out2[(long)b * E + e] = re;
    }
}

// ---------------------------------------------------------------------------
// k_final: one batch row per block. Center scores, top-2 (+index), edge
// mean/var, uncertainty term, risk.
// ---------------------------------------------------------------------------
__global__ __launch_bounds__(256) void k_final(
    const void* __restrict__ amask, const void* __restrict__ emask,
    const int* __restrict__ actions, const float* __restrict__ unc,
    const int* __restrict__ flagp,
    float* __restrict__ out0, float* __restrict__ out1,
    const float* __restrict__ out2,
    float* __restrict__ out3, float* __restrict__ out4)
{
    __shared__ float red[256];
    __shared__ int ridx[256];
    int t = threadIdx.x;
    int b = blockIdx.x;
    int flag = *flagp;

    float am = mask_val(amask, (long)b * N + t, flag);
    float raw = out0[(long)b * N + t];

    float sum = block_sum(raw, red);
    float cnt = block_sum(am, red);
    float denom = fmaxf(cnt, 1.f);

    float rs = (raw - sum / denom) * am;
    out0[(long)b * N + t] = rs;

    float masked = (am != 0.f) ? rs : -1e9f;

    // top-1 with index (ties -> lower index, matching lax.top_k)
    red[t] = masked; ridx[t] = t; __syncthreads();
    for (int s = 128; s > 0; s >>= 1) {
        if (t < s) {
            float o = red[t + s]; int oi = ridx[t + s];
            if (o > red[t] || (o == red[t] && oi < ridx[t])) { red[t] = o; ridx[t] = oi; }
        }
        __syncthreads();
    }
    float v1 = red[0]; int i1 = ridx[0]; __syncthreads();

    // top-2 value
    float m2 = (t == i1) ? -1e9f : masked;
    red[t] = m2; __syncthreads();
    for (int s = 128; s > 0; s >>= 1) {
        if (t < s) red[t] = fmaxf(red[t], red[t + s]);
        __syncthreads();
    }
    float v2 = red[0]; __syncthreads();
    float rmargin = v1 - v2;

    // uncertainty term
    int a = actions[(long)b * N + t];
    a = min(max(a, 0), U - 1);
    float su = block_sum(unc[(long)b * U + a] * am, red);
    float unc_term = su / denom;

    // edge mean / variance (two-pass, values kept in registers)
    float x[4], em[4];
    float S1 = 0.f, ce = 0.f;
    #pragma unroll
    for (int q = 0; q < 4; q++) {
        long idx = (long)b * E + t + 256 * q;
        x[q] = out2[idx];                     // already masked (0 where em==0)
        em[q] = mask_val(emask, idx, flag);
        S1 += x[q]; ce += em[q];
    }
    float S1t = block_sum(S1, red);
    float cet = block_sum(ce, red);
    float mean = S1t / fmaxf(cet, 1.f);
    float v = 0.f;
    #pragma unroll
    for (int q = 0; q < 4; q++) {
        float dd = x[q] - mean;
        v = fmaf(em[q] * dd, dd, v);
    }
    float vt = block_sum(v, red);
    float var = vt / fmaxf(cet, 1.f);
    float evar = (cet > 1.f) ? var : 0.f;

    if (t == 0) {
        out1[b] = rmargin;
        out3[b] = (float)i1;
        float sig = 1.f / (1.f + expf(rmargin));   // sigmoid(-margin)
        float riskv = sig + 0.2f * evar + 0.1f * unc_term;
        out4[b] = fminf(fmaxf(riskv, 0.f), 1.f);
    }
}

// ---------------------------------------------------------------------------
extern "C" void kernel_launch(void* const* d_in, const int* in_sizes, int n_in,
                              void* d_out, int out_size, void* d_ws, size_t ws_size,
                              hipStream_t stream) {
    const float* feat   = (const float*)d_in[0];
    const float* cs     = (const float*)d_in[1];
    const float* marg   = (const float*)d_in[2];
    const float* brisk  = (const float*)d_in[3];
    const float* es     = (const float*)d_in[4];
    const float* coords = (const float*)d_in[5];
    const float* unc    = (const float*)d_in[6];
    const float* Wc1    = (const float*)d_in[7];
    const float* bc1    = (const float*)d_in[8];
    const float* Wc2    = (const float*)d_in[9];
    const float* bc2    = (const float*)d_in[10];
    const float* Wn1    = (const float*)d_in[11];
    const float* bn1    = (const float*)d_in[12];
    const float* Wn2    = (const float*)d_in[13];
    const float* bn2    = (const float*)d_in[14];
    const float* We1    = (const float*)d_in[15];
    const float* be1    = (const float*)d_in[16];
    const float* We2    = (const float*)d_in[17];
    const float* be2    = (const float*)d_in[18];
    const float* Wg     = (const float*)d_in[19];
    const float* bg     = (const float*)d_in[20];
    const void*  amask  = d_in[21];
    const void*  emask  = d_in[22];
    const int*   actions= (const int*)d_in[23];
    const int*   edges  = (const int*)d_in[24];

    float* out0 = (float*)d_out;           // refined_scores (B,N)
    float* out1 = out0 + (long)B * N;      // refined_margin (B,)
    float* out2 = out1 + B;                // refined_edge (B,E)
    float* out3 = out2 + (long)B * E;      // top_idx (B,) as float
    float* out4 = out3 + B;                // refined_risk (B,)
    float* out5 = out4 + B;                // refine_gate (B,)

    float* base_n = (float*)d_ws;
    float* base_e = base_n + (long)B * H;
    int*   flag   = (int*)(base_e + (long)B * H);

    k_detect<<<1, 256, 0, stream>>>((const unsigned int*)amask, flag);
    k_h<<<B / 4, 256, 0, stream>>>(feat, Wc1, bc1, Wc2, bc2, Wn1, bn1, We1, be1,
                                   Wg, bg, marg, brisk, base_n, base_e, out5);
    k_node<<<B / 4, 256, 0, stream>>>(cs, coords, unc, actions, amask,
                                      Wn1, Wn2, bn2, base_n, out5, flag, out0);
    k_edge<<<B, 256, 0, stream>>>(es, coords, edges, emask,
                                  We1, We2, be2, base_e, out5, flag, out2);
    k_final<<<B, 256, 0, stream>>>(amask, emask, actions, unc, flag,
                                   out0, out1, out2, out3, out4);
}

// Round 2
// 90.460 us; speedup vs baseline: 1.5130x; 1.5130x over previous
//
#include <hip/hip_runtime.h>
#include <math.h>

#define B 512
#define N 256
#define E 1024
#define D 256
#define H 256
#define C 8
#define U 64

// ---------------------------------------------------------------------------
// Mask dtype sniffing: flag 0 = int32 words, 1 = byte-packed bool, 2 = float32
// ---------------------------------------------------------------------------
__device__ __forceinline__ float mask_val(const void* m, long i, int flag) {
    if (flag == 1) return ((const unsigned char*)m)[i] ? 1.f : 0.f;
    if (flag == 2) return (((const float*)m)[i] != 0.f) ? 1.f : 0.f;
    return ((const int*)m)[i] ? 1.f : 0.f;
}

// block-wide sum reduction (256 threads)
__device__ __forceinline__ float block_sum(float v, float* red) {
    int t = threadIdx.x;
    red[t] = v; __syncthreads();
    for (int s = 128; s > 0; s >>= 1) {
        if (t < s) red[t] += red[t + s];
        __syncthreads();
    }
    float r = red[0]; __syncthreads();
    return r;
}

// ---------------------------------------------------------------------------
// k_h: per-batch trunk, 2 rows/block, 512 threads (8 waves, grid=256 -> 1/CU).
//   P1: A = relu(feat@Wc1+bc1)   thread (w=row, c=col), full K, unroll-16
//   P2: h = relu(A@Wc2+bc2)
//   gate reduce per row
//   P3: thread-half w selects matrix (0: Wn1->base_n, 1: We1->base_e),
//       computes BOTH rows (no redundant weight loads).
// Block 0 additionally sniffs the action_mask dtype into *flag.
// ---------------------------------------------------------------------------
__global__ __launch_bounds__(512) void k_h(
    const float* __restrict__ feat,
    const float* __restrict__ Wc1, const float* __restrict__ bc1,
    const float* __restrict__ Wc2, const float* __restrict__ bc2,
    const float* __restrict__ Wn1, const float* __restrict__ bn1,
    const float* __restrict__ We1, const float* __restrict__ be1,
    const float* __restrict__ Wg,  const float* __restrict__ bg,
    const float* __restrict__ margin, const float* __restrict__ brisk,
    const unsigned int* __restrict__ amask_words,
    float* __restrict__ base_n, float* __restrict__ base_e,
    float* __restrict__ out_gate, int* __restrict__ flag)
{
    __shared__ __align__(16) float sF[2][256];
    __shared__ __align__(16) float sH[2][256];
    __shared__ float red[512];
    __shared__ int cls0, cls1;

    int t = threadIdx.x;
    int w = t >> 8;        // 0/1: row in P1/P2, matrix in P3
    int c = t & 255;
    int b0 = blockIdx.x * 2;
    int b = b0 + w;

    // ---- mask dtype detection (block 0 only; block-uniform syncs) ----
    if (blockIdx.x == 0) {
        if (t == 0) { cls0 = 0; cls1 = 0; }
        __syncthreads();
        if (t < 256) {
            unsigned int wd = amask_words[t];
            if (wd != 0u && wd != 1u) {
                if (wd == 0x3f800000u) atomicOr(&cls1, 1);
                else                   atomicOr(&cls0, 1);
            }
        }
        __syncthreads();
        if (t == 0) *flag = cls0 ? 1 : (cls1 ? 2 : 0);
    }

    sF[w][c] = feat[(long)b * D + c];
    __syncthreads();

    // ---- P1: relu(feat @ Wc1 + bc1) -> sH ----
    {
        float acc[4] = {bc1[c], 0.f, 0.f, 0.f};
        const float* Wp = Wc1 + c;
        for (int d0 = 0; d0 < D; d0 += 16) {
            float wv[16];
            #pragma unroll
            for (int k = 0; k < 16; k++) wv[k] = Wp[(long)(d0 + k) * H];
            #pragma unroll
            for (int k = 0; k < 16; k++)
                acc[k & 3] = fmaf(sF[w][d0 + k], wv[k], acc[k & 3]);
        }
        float a = fmaxf((acc[0] + acc[1]) + (acc[2] + acc[3]), 0.f);
        sH[w][c] = a;
    }
    __syncthreads();

    // ---- P2: h = relu(A @ Wc2 + bc2) -> sF ----
    {
        float acc[4] = {bc2[c], 0.f, 0.f, 0.f};
        const float* Wp = Wc2 + c;
        for (int d0 = 0; d0 < H; d0 += 16) {
            float wv[16];
            #pragma unroll
            for (int k = 0; k < 16; k++) wv[k] = Wp[(long)(d0 + k) * H];
            #pragma unroll
            for (int k = 0; k < 16; k++)
                acc[k & 3] = fmaf(sH[w][d0 + k], wv[k], acc[k & 3]);
        }
        float a = fmaxf((acc[0] + acc[1]) + (acc[2] + acc[3]), 0.f);
        __syncthreads();
        sF[w][c] = a;                 // sF now holds h for both rows
    }
    __syncthreads();

    // ---- gate per row ----
    red[t] = sF[w][c] * Wg[c];
    __syncthreads();
    for (int s = 128; s > 0; s >>= 1) {
        if (c < s) red[t] += red[t + s];
        __syncthreads();
    }
    if (c == 0) {
        float lg = 1.f / (1.f + expf(-(red[t] + bg[0])));
        out_gate[b] = ((margin[b] < 0.2f) || (brisk[b] > 0.6f) || (lg > 0.5f)) ? 1.f : 0.f;
    }

    // ---- P3: base_n / base_e (thread-half = matrix, both rows) ----
    {
        const float* W3  = w ? (We1 + c) : (Wn1 + c);
        float bias       = w ? be1[c]    : bn1[c];
        float* dst       = w ? base_e    : base_n;
        float aA[2] = {bias, 0.f};
        float aB[2] = {bias, 0.f};
        for (int d0 = 0; d0 < H; d0 += 16) {
            float wv[16];
            #pragma unroll
            for (int k = 0; k < 16; k++) wv[k] = W3[(long)(d0 + k) * H];
            #pragma unroll
            for (int k = 0; k < 16; k++) {
                aA[k & 1] = fmaf(sF[0][d0 + k], wv[k], aA[k & 1]);
                aB[k & 1] = fmaf(sF[1][d0 + k], wv[k], aB[k & 1]);
            }
        }
        dst[(long)b0 * H + c]       = aA[0] + aA[1];
        dst[(long)(b0 + 1) * H + c] = aB[0] + aB[1];
    }
}

// ---------------------------------------------------------------------------
// k_ne: merged node+edge refinement. Blocks [0,128): node (4 rows each);
// blocks [128,640): edge (1 row each). 256 threads.
// ---------------------------------------------------------------------------
__global__ __launch_bounds__(256) void k_ne(
    // node inputs
    const float* __restrict__ cs, const float* __restrict__ coords,
    const float* __restrict__ unc, const int* __restrict__ actions,
    const void* __restrict__ amask,
    const float* __restrict__ Wn1, const float* __restrict__ Wn2,
    const float* __restrict__ bn2, const float* __restrict__ base_n,
    // edge inputs
    const float* __restrict__ es, const int* __restrict__ edges,
    const void* __restrict__ emask,
    const float* __restrict__ We1, const float* __restrict__ We2,
    const float* __restrict__ be2, const float* __restrict__ base_e,
    // common
    const float* __restrict__ gate, const int* __restrict__ flagp,
    float* __restrict__ out0, float* __restrict__ out2)
{
    __shared__ __align__(16) float sW[256][12];
    __shared__ __align__(16) float sRest[256 * 9];
    int t = threadIdx.x;
    int flag = *flagp;

    if (blockIdx.x < 128) {
        // ================= NODE =================
        float (*sB)[256] = (float (*)[256])sRest;
        int b0 = blockIdx.x * 4;

        #pragma unroll
        for (int k = 0; k < 10; k++) sW[t][k] = Wn1[(H + k) * H + t];
        sW[t][10] = Wn2[t];
        sW[t][11] = 0.f;
        #pragma unroll
        for (int r = 0; r < 4; r++) sB[r][t] = base_n[(long)(b0 + r) * H + t];
        __syncthreads();

        int w = t >> 6, lane = t & 63;
        int b = b0 + w;
        float g = gate[b];
        float bn2v = bn2[0];

        float f[4][10], acc[4], amv[4];
        #pragma unroll
        for (int q = 0; q < 4; q++) {
            int n = lane + 64 * q;
            const float4* cp = (const float4*)(coords + ((long)b * N + n) * C);
            float4 c0 = cp[0], c1 = cp[1];
            f[q][0] = c0.x; f[q][1] = c0.y; f[q][2] = c0.z; f[q][3] = c0.w;
            f[q][4] = c1.x; f[q][5] = c1.y; f[q][6] = c1.z; f[q][7] = c1.w;
            f[q][8] = cs[(long)b * N + n];
            int a = actions[(long)b * N + n];
            a = min(max(a, 0), U - 1);
            f[q][9] = unc[(long)b * U + a];
            amv[q] = mask_val(amask, (long)b * N + n, flag);
            acc[q] = bn2v;
        }

        for (int j = 0; j < H; j++) {
            float base = sB[w][j];
            float w2 = sW[j][10];
            #pragma unroll
            for (int q = 0; q < 4; q++) {
                float z = base;
                #pragma unroll
                for (int k = 0; k < 10; k++) z = fmaf(f[q][k], sW[j][k], z);
                acc[q] = fmaf(fmaxf(z, 0.f), w2, acc[q]);
            }
        }

        #pragma unroll
        for (int q = 0; q < 4; q++) {
            int n = lane + 64 * q;
            float am = amv[q];
            float nd = acc[q] * am;
            float raw = (f[q][8] + g * 0.1f * nd) * am;
            out0[(long)b * N + n] = raw;
        }
    } else {
        // ================= EDGE =================
        float* sB = sRest;                       // [256]
        float (*sC)[8] = (float (*)[8])(sRest + 256);
        int b = blockIdx.x - 128;

        #pragma unroll
        for (int k = 0; k < 10; k++) sW[t][k] = We1[(H + k) * H + t];
        sW[t][10] = We2[t];
        sW[t][11] = 0.f;
        sB[t] = base_e[(long)b * H + t];
        {
            float4* sc4 = (float4*)&sC[0][0];
            const float4* g4 = (const float4*)(coords + (long)b * N * C);
            sc4[t] = g4[t];
            sc4[t + 256] = g4[t + 256];
        }
        __syncthreads();

        float g = gate[b];
        float be2v = be2[0];

        float f[4][10], acc[4], emv[4];
        #pragma unroll
        for (int q = 0; q < 4; q++) {
            int e = t + 256 * q;
            int2 ev = ((const int2*)edges)[(long)b * E + e];
            int s0 = min(max(ev.x, 0), N - 1);
            int d0 = min(max(ev.y, 0), N - 1);
            #pragma unroll
            for (int k = 0; k < 8; k++) f[q][k] = sC[d0][k] - sC[s0][k];
            f[q][8] = es[(long)b * E + e];
            emv[q] = mask_val(emask, (long)b * E + e, flag);
            f[q][9] = emv[q];
            acc[q] = be2v;
        }

        for (int j = 0; j < H; j++) {
            float base = sB[j];
            float w2 = sW[j][10];
            #pragma unroll
            for (int q = 0; q < 4; q++) {
                float z = base;
                #pragma unroll
                for (int k = 0; k < 10; k++) z = fmaf(f[q][k], sW[j][k], z);
                acc[q] = fmaf(fmaxf(z, 0.f), w2, acc[q]);
            }
        }

        #pragma unroll
        for (int q = 0; q < 4; q++) {
            int e = t + 256 * q;
            float re = (emv[q] != 0.f) ? (f[q][8] + g * 0.1f * acc[q]) : 0.f;
            out2[(long)b * E + e] = re;
        }
    }
}

// ---------------------------------------------------------------------------
// k_final: one batch row per block. Center scores, top-2 (+index), edge
// mean/var, uncertainty term, risk.
// ---------------------------------------------------------------------------
__global__ __launch_bounds__(256) void k_final(
    const void* __restrict__ amask, const void* __restrict__ emask,
    const int* __restrict__ actions, const float* __restrict__ unc,
    const int* __restrict__ flagp,
    float* __restrict__ out0, float* __restrict__ out1,
    const float* __restrict__ out2,
    float* __restrict__ out3, float* __restrict__ out4)
{
    __shared__ float red[256];
    __shared__ int ridx[256];
    int t = threadIdx.x;
    int b = blockIdx.x;
    int flag = *flagp;

    float am = mask_val(amask, (long)b * N + t, flag);
    float raw = out0[(long)b * N + t];

    float sum = block_sum(raw, red);
    float cnt = block_sum(am, red);
    float denom = fmaxf(cnt, 1.f);

    float rs = (raw - sum / denom) * am;
    out0[(long)b * N + t] = rs;

    float masked = (am != 0.f) ? rs : -1e9f;

    // top-1 with index (ties -> lower index)
    red[t] = masked; ridx[t] = t; __syncthreads();
    for (int s = 128; s > 0; s >>= 1) {
        if (t < s) {
            float o = red[t + s]; int oi = ridx[t + s];
            if (o > red[t] || (o == red[t] && oi < ridx[t])) { red[t] = o; ridx[t] = oi; }
        }
        __syncthreads();
    }
    float v1 = red[0]; int i1 = ridx[0]; __syncthreads();

    // top-2 value
    float m2 = (t == i1) ? -1e9f : masked;
    red[t] = m2; __syncthreads();
    for (int s = 128; s > 0; s >>= 1) {
        if (t < s) red[t] = fmaxf(red[t], red[t + s]);
        __syncthreads();
    }
    float v2 = red[0]; __syncthreads();
    float rmargin = v1 - v2;

    // uncertainty term
    int a = actions[(long)b * N + t];
    a = min(max(a, 0), U - 1);
    float su = block_sum(unc[(long)b * U + a] * am, red);
    float unc_term = su / denom;

    // edge mean / variance
    float x[4], em[4];
    float S1 = 0.f, ce = 0.f;
    #pragma unroll
    for (int q = 0; q < 4; q++) {
        long idx = (long)b * E + t + 256 * q;
        x[q] = out2[idx];
        em[q] = mask_val(emask, idx, flag);
        S1 += x[q]; ce += em[q];
    }
    float S1t = block_sum(S1, red);
    float cet = block_sum(ce, red);
    float mean = S1t / fmaxf(cet, 1.f);
    float v = 0.f;
    #pragma unroll
    for (int q = 0; q < 4; q++) {
        float dd = x[q] - mean;
        v = fmaf(em[q] * dd, dd, v);
    }
    float vt = block_sum(v, red);
    float var = vt / fmaxf(cet, 1.f);
    float evar = (cet > 1.f) ? var : 0.f;

    if (t == 0) {
        out1[b] = rmargin;
        out3[b] = (float)i1;
        float sig = 1.f / (1.f + expf(rmargin));
        float riskv = sig + 0.2f * evar + 0.1f * unc_term;
        out4[b] = fminf(fmaxf(riskv, 0.f), 1.f);
    }
}

// ---------------------------------------------------------------------------
extern "C" void kernel_launch(void* const* d_in, const int* in_sizes, int n_in,
                              void* d_out, int out_size, void* d_ws, size_t ws_size,
                              hipStream_t stream) {
    const float* feat   = (const float*)d_in[0];
    const float* cs     = (const float*)d_in[1];
    const float* marg   = (const float*)d_in[2];
    const float* brisk  = (const float*)d_in[3];
    const float* es     = (const float*)d_in[4];
    const float* coords = (const float*)d_in[5];
    const float* unc    = (const float*)d_in[6];
    const float* Wc1    = (const float*)d_in[7];
    const float* bc1    = (const float*)d_in[8];
    const float* Wc2    = (const float*)d_in[9];
    const float* bc2    = (const float*)d_in[10];
    const float* Wn1    = (const float*)d_in[11];
    const float* bn1    = (const float*)d_in[12];
    const float* Wn2    = (const float*)d_in[13];
    const float* bn2    = (const float*)d_in[14];
    const float* We1    = (const float*)d_in[15];
    const float* be1    = (const float*)d_in[16];
    const float* We2    = (const float*)d_in[17];
    const float* be2    = (const float*)d_in[18];
    const float* Wg     = (const float*)d_in[19];
    const float* bg     = (const float*)d_in[20];
    const void*  amask  = d_in[21];
    const void*  emask  = d_in[22];
    const int*   actions= (const int*)d_in[23];
    const int*   edges  = (const int*)d_in[24];

    float* out0 = (float*)d_out;           // refined_scores (B,N)
    float* out1 = out0 + (long)B * N;      // refined_margin (B,)
    float* out2 = out1 + B;                // refined_edge (B,E)
    float* out3 = out2 + (long)B * E;      // top_idx (B,) as float
    float* out4 = out3 + B;                // refined_risk (B,)
    float* out5 = out4 + B;                // refine_gate (B,)

    float* base_n = (float*)d_ws;
    float* base_e = base_n + (long)B * H;
    int*   flag   = (int*)(base_e + (long)B * H);

    k_h<<<B / 2, 512, 0, stream>>>(feat, Wc1, bc1, Wc2, bc2, Wn1, bn1, We1, be1,
                                   Wg, bg, marg, brisk,
                                   (const unsigned int*)amask,
                                   base_n, base_e, out5, flag);
    k_ne<<<128 + B, 256, 0, stream>>>(cs, coords, unc, actions, amask,
                                      Wn1, Wn2, bn2, base_n,
                                      es, edges, emask,
                                      We1, We2, be2, base_e,
                                      out5, flag, out0, out2);
    k_final<<<B, 256, 0, stream>>>(amask, emask, actions, unc, flag,
                                   out0, out1, out2, out3, out4);
}